// Round 7
// baseline (1609.140 us; speedup 1.0000x reference)
//
#include <hip/hip_runtime.h>

// SignNet GINE: 3 layers, signs batched as 2N interleaved rows (2i=+x, 2i+1=-x).
// CSR gather aggregation; MFMA edge-embedding (agg128) and MFMA node MLPs with
// hi/lo-split bf16 operands (f32-grade precision on both weights and activations).
constexpr int DHID = 128;

typedef __attribute__((ext_vector_type(8))) short bf16x8v;
typedef __attribute__((ext_vector_type(4))) float f32x4v;

__device__ __forceinline__ float b2f(unsigned short u) {
    union { unsigned int i; float f; } v;
    v.i = ((unsigned int)u) << 16;
    return v.f;
}
__device__ __forceinline__ unsigned short f2b(float f) {
    union { float f; unsigned int i; } v;
    v.f = f;
    unsigned int x = v.i;
    return (unsigned short)((x + 0x7fff + ((x >> 16) & 1)) >> 16);
}
__device__ __forceinline__ unsigned int pack2(float a, float b) {
    return (unsigned int)f2b(a) | ((unsigned int)f2b(b) << 16);
}
__device__ __forceinline__ float bres(float w) { return w - b2f(f2b(w)); }
__device__ __forceinline__ void dot2b(float& acc, unsigned int a, unsigned int b) {
    asm("v_dot2_f32_bf16 %0, %1, %2, %0" : "+v"(acc) : "v"(a), "v"(b));
}

__global__ __launch_bounds__(256)
void init_h0(const float* __restrict__ x, float* __restrict__ H0,
             unsigned short* __restrict__ H0B, int n) {
    int i = blockIdx.x * 256 + threadIdx.x;   // over N*16
    if (i < n * 16) {
        int r = i >> 4, c = i & 15;
        float v = x[i];
        H0[(size_t)(2 * r) * 16 + c] = v;
        H0[(size_t)(2 * r + 1) * 16 + c] = -v;
        H0B[(size_t)(2 * r) * 16 + c] = f2b(v);
        H0B[(size_t)(2 * r + 1) * 16 + c] = f2b(-v);
    }
}

__global__ __launch_bounds__(256)
void sum_signs(const float* __restrict__ H3, float* __restrict__ S, int n) {
    int i = blockIdx.x * 256 + threadIdx.x;   // over N*64
    if (i < n * 64) {
        int r = i >> 6;
        S[i] = H3[i + (size_t)r * 64] + H3[i + (size_t)r * 64 + 64];
    }
}

// ---------------- CSR build ----------------
__global__ __launch_bounds__(256)
void csr_count(const int* __restrict__ DST, int* __restrict__ deg, int E_) {
    int e = blockIdx.x * 256 + threadIdx.x;
    if (e < E_) atomicAdd(&deg[DST[e]], 1);
}

__global__ __launch_bounds__(256)
void scan1(const int* __restrict__ deg, int* __restrict__ off,
           int* __restrict__ bsum, int n) {
    __shared__ int s[256];
    int tid = threadIdx.x;
    int i = blockIdx.x * 256 + tid;
    int v = (i < n) ? deg[i] : 0;
    s[tid] = v;
    __syncthreads();
    for (int d = 1; d < 256; d <<= 1) {
        int t = (tid >= d) ? s[tid - d] : 0;
        __syncthreads();
        if (tid >= d) s[tid] += t;
        __syncthreads();
    }
    if (i < n) off[i] = s[tid] - v;
    if (tid == 255) bsum[blockIdx.x] = s[255];
}

__global__ __launch_bounds__(256)
void scan2(int* __restrict__ bsum, int nb) {
    __shared__ int s[256];
    int tid = threadIdx.x;
    int v = (tid < nb) ? bsum[tid] : 0;
    s[tid] = v;
    __syncthreads();
    for (int d = 1; d < 256; d <<= 1) {
        int t = (tid >= d) ? s[tid - d] : 0;
        __syncthreads();
        if (tid >= d) s[tid] += t;
        __syncthreads();
    }
    if (tid < nb) bsum[tid] = s[tid] - v;
}

__global__ __launch_bounds__(256)
void scan3(int* __restrict__ off, int* __restrict__ pos,
           const int* __restrict__ bsum, const int* __restrict__ deg, int n) {
    int i = blockIdx.x * 256 + threadIdx.x;
    if (i < n) {
        int o = off[i] + bsum[blockIdx.x];
        off[i] = o;
        pos[i] = o;
        if (i == n - 1) off[n] = o + deg[i];
    }
}

// Fill CSR: src index + edge attrs gathered into CSR order as bf16 (32B/edge).
__global__ __launch_bounds__(256)
void csr_fill(const int* __restrict__ SRC, const int* __restrict__ DST,
              const float* __restrict__ EA, int* __restrict__ pos,
              int* __restrict__ csrsrc, uint4* __restrict__ EABS, int E_) {
    int e = blockIdx.x * 256 + threadIdx.x;
    if (e < E_) {
        int d = DST[e];
        int j = atomicAdd(&pos[d], 1);
        csrsrc[j] = SRC[e];
        const float4* ea4 = (const float4*)(EA + (size_t)e * 16);
        float4 q0 = ea4[0], q1 = ea4[1], q2 = ea4[2], q3 = ea4[3];
        uint4 o0, o1;
        o0.x = pack2(q0.x, q0.y); o0.y = pack2(q0.z, q0.w);
        o0.z = pack2(q1.x, q1.y); o0.w = pack2(q1.z, q1.w);
        o1.x = pack2(q2.x, q2.y); o1.y = pack2(q2.z, q2.w);
        o1.z = pack2(q3.x, q3.y); o1.w = pack2(q3.z, q3.w);
        EABS[(size_t)2 * j] = o0;
        EABS[(size_t)2 * j + 1] = o1;
    }
}

// ---------------- gather aggregation ----------------
// din=128, MFMA edge-embedding (verified round 6). One wave per node.
__global__ __launch_bounds__(256)
void agg_gather128(const int* __restrict__ CSRS, const int* __restrict__ OFF,
                   const unsigned short* __restrict__ EABS,
                   const float* __restrict__ WE, const float* __restrict__ BE,
                   const unsigned short* __restrict__ HB,
                   float* __restrict__ AGG, int n) {
    const int tid = threadIdx.x;
    const int lane = tid & 63;
    const int node = blockIdx.x * 4 + (tid >> 6);
    if (node >= n) return;
    const int col = lane & 15;
    const int grp = lane >> 4;          // 0..3
    const int klo = (grp & 1) * 8;

    bf16x8v bfrag[8];
#pragma unroll
    for (int cb = 0; cb < 8; ++cb) {
        bf16x8v b;
#pragma unroll
        for (int i = 0; i < 8; ++i) {
            float w = WE[(klo + i) * 128 + cb * 16 + col];
            unsigned short hi = f2b(w);
            unsigned short lo = f2b(bres(w));
            b[i] = (short)(grp >= 2 ? lo : hi);
        }
        bfrag[cb] = b;
    }
    float bias[8];
#pragma unroll
    for (int cb = 0; cb < 8; ++cb) bias[cb] = BE[cb * 16 + col];

    float asum0[8], asum1[8];
#pragma unroll
    for (int cb = 0; cb < 8; ++cb) { asum0[cb] = 0.f; asum1[cb] = 0.f; }

    const int j0 = OFF[node], j1 = OFF[node + 1];
    const char* ebase = (const char*)EABS;

    for (int base = j0; base < j1; base += 16) {
        const int rem = j1 - base;
        uint4 a4 = *(const uint4*)(ebase + ((size_t)(base + col) << 5) +
                                   ((grp & 1) << 4));
        bf16x8v afrag = __builtin_bit_cast(bf16x8v, a4);
        f32x4v ev[8];
#pragma unroll
        for (int cb = 0; cb < 8; ++cb) {
            f32x4v c = {bias[cb], bias[cb], bias[cb], bias[cb]};
            ev[cb] = __builtin_amdgcn_mfma_f32_16x16x32_bf16(afrag, bfrag[cb], c,
                                                             0, 0, 0);
        }
        float vmask[4];
        const unsigned short* hp[4];
#pragma unroll
        for (int r = 0; r < 4; ++r) {
            int t = grp * 4 + r;
            bool valid = t < rem;
            vmask[r] = valid ? 1.f : 0.f;
            int ji = valid ? (base + t) : j0;
            int src = CSRS[ji];
            hp[r] = HB + (size_t)(2 * src) * 128;
        }
#pragma unroll
        for (int cb = 0; cb < 8; ++cb) {
            float p0 = 0.f, p1 = 0.f;
#pragma unroll
            for (int r = 0; r < 4; ++r) {
                float e = ev[cb][r];
                float h0 = b2f(hp[r][cb * 16 + col]);
                float h1 = b2f(hp[r][128 + cb * 16 + col]);
                p0 += fmaxf(h0 + e, 0.f) * vmask[r];
                p1 += fmaxf(h1 + e, 0.f) * vmask[r];
            }
            p0 += __shfl_xor(p0, 16);
            p0 += __shfl_xor(p0, 32);
            p1 += __shfl_xor(p1, 16);
            p1 += __shfl_xor(p1, 32);
            asum0[cb] += p0;
            asum1[cb] += p1;
        }
    }
    float* arow = AGG + (size_t)(2 * node) * 128;
#pragma unroll
    for (int cb = 0; cb < 8; ++cb) {
        if (grp == (cb & 3)) {
            arow[cb * 16 + col] = asum0[cb];
            arow[128 + cb * 16 + col] = asum1[cb];
        }
    }
}

// din=16: half-wave (32 lanes) per node.
__global__ __launch_bounds__(256)
void agg_gather16(const int* __restrict__ CSRS, const int* __restrict__ OFF,
                  const uint4* __restrict__ EABS, const float* __restrict__ WE,
                  const float* __restrict__ BE,
                  const unsigned short* __restrict__ HB,
                  float* __restrict__ AGG, int n) {
    const int l = threadIdx.x & 31;
    const int node = blockIdx.x * 8 + (threadIdx.x >> 5);
    if (node >= n) return;
    const int s = l >> 4;
    const int c = l & 15;
    unsigned int wh[8], wl[8];
#pragma unroll
    for (int t = 0; t < 8; ++t) {
        float a0 = WE[(2 * t) * 16 + c], a1 = WE[(2 * t + 1) * 16 + c];
        wh[t] = pack2(a0, a1);
        wl[t] = pack2(bres(a0), bres(a1));
    }
    const float bev = BE[c];
    float acc = 0.f;
    const int j0 = OFF[node], j1 = OFF[node + 1];
#pragma unroll 4
    for (int j = j0; j < j1; ++j) {
        int src = CSRS[j];
        uint4 p = EABS[(size_t)2 * j], q = EABS[(size_t)2 * j + 1];
        float ec = bev;
        dot2b(ec, p.x, wh[0]); dot2b(ec, p.y, wh[1]);
        dot2b(ec, p.z, wh[2]); dot2b(ec, p.w, wh[3]);
        dot2b(ec, q.x, wh[4]); dot2b(ec, q.y, wh[5]);
        dot2b(ec, q.z, wh[6]); dot2b(ec, q.w, wh[7]);
        dot2b(ec, p.x, wl[0]); dot2b(ec, p.y, wl[1]);
        dot2b(ec, p.z, wl[2]); dot2b(ec, p.w, wl[3]);
        dot2b(ec, q.x, wl[4]); dot2b(ec, q.y, wl[5]);
        dot2b(ec, q.z, wl[6]); dot2b(ec, q.w, wl[7]);
        float hv = b2f(HB[(size_t)(2 * src + s) * 16 + c]);
        acc += fmaxf(hv + ec, 0.f);
    }
    AGG[(size_t)(2 * node + s) * 16 + c] = acc;
}

// ---------------- MFMA node MLP ----------------
// OUT = maybe_relu( relu((X [+AGG]) @ W1 + b1) @ W2 + b2 ), DHID=128.
// 64-row tile per block, 4 waves; wave owns 2 hidden col-blocks.
// Precision: B-frag = [W_hi | W_lo] in the two K-halves; activations via
//   acc = mfma([Xhi|Xhi], B) + mfma([Xlo|0], B)   (drops only xlo*wlo ~2^-16).
template <int DIN, int DOUT, bool RELU_OUT, bool HAS_AGG, bool WRITE_B>
__global__ __launch_bounds__(256)
void node_mlp_mfma(const float* __restrict__ X, const float* __restrict__ AGG,
                   const float* __restrict__ W1, const float* __restrict__ B1,
                   const float* __restrict__ W2, const float* __restrict__ B2,
                   float* __restrict__ OUT, unsigned short* __restrict__ OUTB,
                   int rows) {
    constexpr int KC1 = DIN / 16;
    constexpr int NB2 = DOUT / 16;
    constexpr int CB2W = (NB2 >= 4) ? NB2 / 4 : 1;
    constexpr int SHS = 136;   // ushort stride: 272B rows, 16B-aligned, bank-spread
    __shared__ unsigned short sHhi[64 * SHS];
    __shared__ unsigned short sHlo[64 * SHS];
    const int tid = threadIdx.x;
    const int w = tid >> 6;
    const int lane = tid & 63;
    const int col = lane & 15;
    const int grp = lane >> 4;
    const int khalf = (grp & 1) * 8;
    const bool hi_lane = grp < 2;
    const int row0 = blockIdx.x * 64;

    // ---- B1 fragments ----
    bf16x8v b1f[2][KC1];
    float bias1[2];
#pragma unroll
    for (int cb = 0; cb < 2; ++cb) {
        const int cbg = 2 * w + cb;
#pragma unroll
        for (int kc = 0; kc < KC1; ++kc) {
            bf16x8v b;
#pragma unroll
            for (int i = 0; i < 8; ++i) {
                float wv = W1[(size_t)(kc * 16 + khalf + i) * DHID + cbg * 16 + col];
                b[i] = (short)(hi_lane ? f2b(wv) : f2b(bres(wv)));
            }
            b1f[cb][kc] = b;
        }
        bias1[cb] = B1[cbg * 16 + col];
    }

    // ---- GEMM1: hidden = relu((X+AGG)@W1 + b1) -> sH hi/lo ----
#pragma unroll
    for (int rg = 0; rg < 4; ++rg) {
        bf16x8v a1[KC1], a2[KC1];
        const int row = row0 + rg * 16 + col;
        const bool rok = row < rows;
#pragma unroll
        for (int kc = 0; kc < KC1; ++kc) {
            float xv[8];
            if (rok) {
                const float4* xp =
                    (const float4*)(X + (size_t)row * DIN + kc * 16 + khalf);
                float4 u0 = xp[0], u1 = xp[1];
                if (HAS_AGG) {
                    const float4* ap =
                        (const float4*)(AGG + (size_t)row * DIN + kc * 16 + khalf);
                    float4 g0 = ap[0], g1 = ap[1];
                    u0.x += g0.x; u0.y += g0.y; u0.z += g0.z; u0.w += g0.w;
                    u1.x += g1.x; u1.y += g1.y; u1.z += g1.z; u1.w += g1.w;
                }
                xv[0] = u0.x; xv[1] = u0.y; xv[2] = u0.z; xv[3] = u0.w;
                xv[4] = u1.x; xv[5] = u1.y; xv[6] = u1.z; xv[7] = u1.w;
            } else {
#pragma unroll
                for (int i = 0; i < 8; ++i) xv[i] = 0.f;
            }
            bf16x8v h, l;
#pragma unroll
            for (int i = 0; i < 8; ++i) {
                unsigned short hv = f2b(xv[i]);
                h[i] = (short)hv;
                float r = xv[i] - b2f(hv);
                l[i] = (short)(hi_lane ? f2b(r) : (unsigned short)0);
            }
            a1[kc] = h;
            a2[kc] = l;
        }
#pragma unroll
        for (int cb = 0; cb < 2; ++cb) {
            const int cbg = 2 * w + cb;
            f32x4v acc = {bias1[cb], bias1[cb], bias1[cb], bias1[cb]};
#pragma unroll
            for (int kc = 0; kc < KC1; ++kc) {
                acc = __builtin_amdgcn_mfma_f32_16x16x32_bf16(a1[kc], b1f[cb][kc],
                                                              acc, 0, 0, 0);
                acc = __builtin_amdgcn_mfma_f32_16x16x32_bf16(a2[kc], b1f[cb][kc],
                                                              acc, 0, 0, 0);
            }
#pragma unroll
            for (int r = 0; r < 4; ++r) {
                float v = fmaxf(acc[r], 0.f);
                unsigned short hv = f2b(v);
                float res = v - b2f(hv);
                const int row_l = rg * 16 + grp * 4 + r;
                sHhi[row_l * SHS + cbg * 16 + col] = hv;
                sHlo[row_l * SHS + cbg * 16 + col] = f2b(res);
            }
        }
    }

    // ---- B2 fragments (after b1f is dead -> register reuse) ----
    bf16x8v b2fr[CB2W][8];
    float bias2[CB2W];
#pragma unroll
    for (int cj = 0; cj < CB2W; ++cj) {
        const int cb2g = (NB2 >= 4) ? (w * CB2W + cj) : 0;
#pragma unroll
        for (int kc = 0; kc < 8; ++kc) {
            bf16x8v b;
#pragma unroll
            for (int i = 0; i < 8; ++i) {
                float wv = W2[(size_t)(kc * 16 + khalf + i) * DOUT + cb2g * 16 + col];
                b[i] = (short)(hi_lane ? f2b(wv) : f2b(bres(wv)));
            }
            b2fr[cj][kc] = b;
        }
        bias2[cj] = B2[cb2g * 16 + col];
    }
    __syncthreads();

    // ---- GEMM2: out = sH @ W2 + b2 ----
    const int rg_lo = (NB2 == 1) ? w : 0;
    const int rg_hi = (NB2 == 1) ? w + 1 : 4;
    for (int rg = rg_lo; rg < rg_hi; ++rg) {
        bf16x8v a1[8], a2[8];
#pragma unroll
        for (int kc = 0; kc < 8; ++kc) {
            const int addr = (rg * 16 + col) * SHS + kc * 16 + khalf;
            a1[kc] = *(const bf16x8v*)&sHhi[addr];
            if (hi_lane) {
                a2[kc] = *(const bf16x8v*)&sHlo[addr];
            } else {
                bf16x8v z;
#pragma unroll
                for (int i = 0; i < 8; ++i) z[i] = 0;
                a2[kc] = z;
            }
        }
#pragma unroll
        for (int cj = 0; cj < CB2W; ++cj) {
            const int cb2g = (NB2 >= 4) ? (w * CB2W + cj) : 0;
            f32x4v acc = {bias2[cj], bias2[cj], bias2[cj], bias2[cj]};
#pragma unroll
            for (int kc = 0; kc < 8; ++kc) {
                acc = __builtin_amdgcn_mfma_f32_16x16x32_bf16(a1[kc], b2fr[cj][kc],
                                                              acc, 0, 0, 0);
                acc = __builtin_amdgcn_mfma_f32_16x16x32_bf16(a2[kc], b2fr[cj][kc],
                                                              acc, 0, 0, 0);
            }
#pragma unroll
            for (int r = 0; r < 4; ++r) {
                const int gr = row0 + rg * 16 + grp * 4 + r;
                if (gr < rows) {
                    float o = acc[r];
                    if (RELU_OUT) o = fmaxf(o, 0.f);
                    OUT[(size_t)gr * DOUT + cb2g * 16 + col] = o;
                    if (WRITE_B) OUTB[(size_t)gr * DOUT + cb2g * 16 + col] = f2b(o);
                }
            }
        }
    }
}

extern "C" void kernel_launch(void* const* d_in, const int* in_sizes, int n_in,
                              void* d_out, int out_size, void* d_ws, size_t ws_size,
                              hipStream_t stream) {
    const float* x = (const float*)d_in[0];
    const float* ea = (const float*)d_in[1];
    const int* esrc = (const int*)d_in[2];
    const int* edst = (const int*)d_in[3];
    const float* we0 = (const float*)d_in[4];
    const float* be0 = (const float*)d_in[5];
    const float* w10 = (const float*)d_in[6];
    const float* b10 = (const float*)d_in[7];
    const float* w20 = (const float*)d_in[8];
    const float* b20 = (const float*)d_in[9];
    const float* we1 = (const float*)d_in[10];
    const float* be1 = (const float*)d_in[11];
    const float* w11 = (const float*)d_in[12];
    const float* b11 = (const float*)d_in[13];
    const float* w21 = (const float*)d_in[14];
    const float* b21 = (const float*)d_in[15];
    const float* we2 = (const float*)d_in[16];
    const float* be2 = (const float*)d_in[17];
    const float* w12 = (const float*)d_in[18];
    const float* b12 = (const float*)d_in[19];
    const float* w22 = (const float*)d_in[20];
    const float* b22 = (const float*)d_in[21];
    const float* rw1 = (const float*)d_in[22];
    const float* rb1 = (const float*)d_in[23];
    const float* rw2 = (const float*)d_in[24];
    const float* rb2 = (const float*)d_in[25];

    const int N = in_sizes[0] / 16;
    const int E = in_sizes[2];
    const int M = 2 * N;

    float* HA = (float*)d_ws;                        // M*128 f32
    float* HB = HA + (size_t)M * 128;                // M*128 f32
    float* AG = HB + (size_t)M * 128;                // M*128 f32
    unsigned short* Hb = (unsigned short*)(AG + (size_t)M * 128);  // M*128 bf16
    unsigned short* EABS = Hb + (size_t)M * 128;     // E*16 bf16, CSR order
    int* deg = (int*)(EABS + (size_t)E * 16);        // N
    int* off = deg + N;                              // N+1
    int* pos = off + N + 1;                          // N
    int* bsum = pos + N;                             // 256
    int* csrsrc = bsum + 256;                        // E

    const int eblocks = (E + 255) / 256;
    const int nblocks = (N + 255) / 256;
    const int mt = (M + 63) / 64;

    // ---- CSR build (once; shared by all 3 layers) ----
    hipMemsetAsync(deg, 0, (size_t)N * sizeof(int), stream);
    csr_count<<<eblocks, 256, 0, stream>>>(edst, deg, E);
    scan1<<<nblocks, 256, 0, stream>>>(deg, off, bsum, N);
    scan2<<<1, 256, 0, stream>>>(bsum, nblocks);
    scan3<<<nblocks, 256, 0, stream>>>(off, pos, bsum, deg, N);
    csr_fill<<<eblocks, 256, 0, stream>>>(esrc, edst, ea, pos, csrsrc,
                                          (uint4*)EABS, E);

    // H0 (M x 16), f32 + bf16
    init_h0<<<(N * 16 + 255) / 256, 256, 0, stream>>>(x, HA, Hb, N);

    // ---- layer 0 (din=16 -> 128) ----
    agg_gather16<<<(N + 7) / 8, 256, 0, stream>>>(csrsrc, off, (const uint4*)EABS,
                                                  we0, be0, Hb, AG, N);
    node_mlp_mfma<16, 128, true, true, true><<<mt, 256, 0, stream>>>(
        HA, AG, w10, b10, w20, b20, HB, Hb, M);

    // ---- layer 1 (128 -> 128) ----
    agg_gather128<<<(N + 3) / 4, 256, 0, stream>>>(csrsrc, off, EABS,
                                                   we1, be1, Hb, AG, N);
    node_mlp_mfma<128, 128, true, true, true><<<mt, 256, 0, stream>>>(
        HB, AG, w11, b11, w21, b21, HA, Hb, M);

    // ---- layer 2 (128 -> 64) ----
    agg_gather128<<<(N + 3) / 4, 256, 0, stream>>>(csrsrc, off, EABS,
                                                   we2, be2, Hb, AG, N);
    node_mlp_mfma<128, 64, false, true, false><<<mt, 256, 0, stream>>>(
        HA, AG, w12, b12, w22, b22, HB, nullptr, M);

    // ---- sign sum + readout (64 -> 128 -> 16) ----
    sum_signs<<<(N * 64 + 255) / 256, 256, 0, stream>>>(HB, AG, N);
    node_mlp_mfma<64, 16, false, false, false><<<(N + 63) / 64, 256, 0, stream>>>(
        AG, nullptr, rw1, rb1, rw2, rb2, (float*)d_out, nullptr, N);
}

// Round 8
// 955.003 us; speedup vs baseline: 1.6850x; 1.6850x over previous
//
#include <hip/hip_runtime.h>

// SignNet GINE: 3 layers, signs batched as 2N interleaved rows (2i=+x, 2i+1=-x).
// CSR gather aggregation. agg128: MFMA edge-embedding -> per-wave LDS tile,
// then vectorized (uint4) H gather + accumulate. VALU node MLP (proven r5).
constexpr int DHID = 128;

typedef __attribute__((ext_vector_type(8))) short bf16x8v;
typedef __attribute__((ext_vector_type(4))) float f32x4v;

__device__ __forceinline__ float b2f(unsigned short u) {
    union { unsigned int i; float f; } v;
    v.i = ((unsigned int)u) << 16;
    return v.f;
}
__device__ __forceinline__ unsigned short f2b(float f) {
    union { float f; unsigned int i; } v;
    v.f = f;
    unsigned int x = v.i;
    return (unsigned short)((x + 0x7fff + ((x >> 16) & 1)) >> 16);
}
__device__ __forceinline__ unsigned int pack2(float a, float b) {
    return (unsigned int)f2b(a) | ((unsigned int)f2b(b) << 16);
}
__device__ __forceinline__ float bres(float w) { return w - b2f(f2b(w)); }
__device__ __forceinline__ void dot2b(float& acc, unsigned int a, unsigned int b) {
    asm("v_dot2_f32_bf16 %0, %1, %2, %0" : "+v"(acc) : "v"(a), "v"(b));
}

__global__ __launch_bounds__(256)
void init_h0(const float* __restrict__ x, float* __restrict__ H0,
             unsigned short* __restrict__ H0B, int n) {
    int i = blockIdx.x * 256 + threadIdx.x;   // over N*16
    if (i < n * 16) {
        int r = i >> 4, c = i & 15;
        float v = x[i];
        H0[(size_t)(2 * r) * 16 + c] = v;
        H0[(size_t)(2 * r + 1) * 16 + c] = -v;
        H0B[(size_t)(2 * r) * 16 + c] = f2b(v);
        H0B[(size_t)(2 * r + 1) * 16 + c] = f2b(-v);
    }
}

__global__ __launch_bounds__(256)
void sum_signs(const float* __restrict__ H3, float* __restrict__ S, int n) {
    int i = blockIdx.x * 256 + threadIdx.x;   // over N*64
    if (i < n * 64) {
        int r = i >> 6;
        S[i] = H3[i + (size_t)r * 64] + H3[i + (size_t)r * 64 + 64];
    }
}

// ---------------- CSR build ----------------
__global__ __launch_bounds__(256)
void csr_count(const int* __restrict__ DST, int* __restrict__ deg, int E_) {
    int e = blockIdx.x * 256 + threadIdx.x;
    if (e < E_) atomicAdd(&deg[DST[e]], 1);
}

__global__ __launch_bounds__(256)
void scan1(const int* __restrict__ deg, int* __restrict__ off,
           int* __restrict__ bsum, int n) {
    __shared__ int s[256];
    int tid = threadIdx.x;
    int i = blockIdx.x * 256 + tid;
    int v = (i < n) ? deg[i] : 0;
    s[tid] = v;
    __syncthreads();
    for (int d = 1; d < 256; d <<= 1) {
        int t = (tid >= d) ? s[tid - d] : 0;
        __syncthreads();
        if (tid >= d) s[tid] += t;
        __syncthreads();
    }
    if (i < n) off[i] = s[tid] - v;
    if (tid == 255) bsum[blockIdx.x] = s[255];
}

__global__ __launch_bounds__(256)
void scan2(int* __restrict__ bsum, int nb) {
    __shared__ int s[256];
    int tid = threadIdx.x;
    int v = (tid < nb) ? bsum[tid] : 0;
    s[tid] = v;
    __syncthreads();
    for (int d = 1; d < 256; d <<= 1) {
        int t = (tid >= d) ? s[tid - d] : 0;
        __syncthreads();
        if (tid >= d) s[tid] += t;
        __syncthreads();
    }
    if (tid < nb) bsum[tid] = s[tid] - v;
}

__global__ __launch_bounds__(256)
void scan3(int* __restrict__ off, int* __restrict__ pos,
           const int* __restrict__ bsum, const int* __restrict__ deg, int n) {
    int i = blockIdx.x * 256 + threadIdx.x;
    if (i < n) {
        int o = off[i] + bsum[blockIdx.x];
        off[i] = o;
        pos[i] = o;
        if (i == n - 1) off[n] = o + deg[i];
    }
}

// Fill CSR: src index + edge attrs gathered into CSR order as bf16 (32B/edge).
__global__ __launch_bounds__(256)
void csr_fill(const int* __restrict__ SRC, const int* __restrict__ DST,
              const float* __restrict__ EA, int* __restrict__ pos,
              int* __restrict__ csrsrc, uint4* __restrict__ EABS, int E_) {
    int e = blockIdx.x * 256 + threadIdx.x;
    if (e < E_) {
        int d = DST[e];
        int j = atomicAdd(&pos[d], 1);
        csrsrc[j] = SRC[e];
        const float4* ea4 = (const float4*)(EA + (size_t)e * 16);
        float4 q0 = ea4[0], q1 = ea4[1], q2 = ea4[2], q3 = ea4[3];
        uint4 o0, o1;
        o0.x = pack2(q0.x, q0.y); o0.y = pack2(q0.z, q0.w);
        o0.z = pack2(q1.x, q1.y); o0.w = pack2(q1.z, q1.w);
        o1.x = pack2(q2.x, q2.y); o1.y = pack2(q2.z, q2.w);
        o1.z = pack2(q3.x, q3.y); o1.w = pack2(q3.z, q3.w);
        EABS[(size_t)2 * j] = o0;
        EABS[(size_t)2 * j + 1] = o1;
    }
}

// ---------------- gather aggregation ----------------
// din=128. One wave per node; 16-edge chunks.
// Phase A: e = EA@We + be on MFMA (hi/lo-split We, verified r6), ev -> LDS
//          (per-wave [16][132] f32 tile; invalid slots poisoned -1e30).
// Phase B: lane owns (sign s, col-octet co) fixed; walks 8 edges (parity ep),
//          H loaded as uint4 (8 bf16), e re-read from LDS as 2x float4.
__global__ __launch_bounds__(256)
void agg_gather128(const int* __restrict__ CSRS, const int* __restrict__ OFF,
                   const unsigned short* __restrict__ EABS,
                   const float* __restrict__ WE, const float* __restrict__ BE,
                   const unsigned short* __restrict__ HB,
                   float* __restrict__ AGG, int n) {
    __shared__ float esm_all[4][16][132];
    const int tid = threadIdx.x;
    const int wv = tid >> 6;
    const int lane = tid & 63;
    const int node = blockIdx.x * 4 + wv;
    if (node >= n) return;
    float (*esm)[132] = esm_all[wv];

    const int col = lane & 15;
    const int grp = lane >> 4;          // 0..3
    const int klo = (grp & 1) * 8;

    // B fragments: We hi/lo packed into the two K-halves (verified r6).
    bf16x8v bfrag[8];
#pragma unroll
    for (int cb = 0; cb < 8; ++cb) {
        bf16x8v b;
#pragma unroll
        for (int i = 0; i < 8; ++i) {
            float w = WE[(klo + i) * 128 + cb * 16 + col];
            unsigned short hi = f2b(w);
            unsigned short lo = f2b(bres(w));
            b[i] = (short)(grp >= 2 ? lo : hi);
        }
        bfrag[cb] = b;
    }
    float bias[8];
#pragma unroll
    for (int cb = 0; cb < 8; ++cb) bias[cb] = BE[cb * 16 + col];

    // Phase-B lane mapping: fixed (sign, col-octet), edge parity split.
    const int o = lane & 31;            // 0..31 octet id
    const int s = o >> 4;               // sign
    const int co = (o & 15) * 8;        // col offset
    const int ep = lane >> 5;           // edge parity

    float acc[8];
#pragma unroll
    for (int i = 0; i < 8; ++i) acc[i] = 0.f;

    const int j0 = OFF[node], j1 = OFF[node + 1];
    const char* ebase = (const char*)EABS;

    for (int base = j0; base < j1; base += 16) {
        const int rem = j1 - base;
        // ---- Phase A: MFMA edge embedding -> esm ----
        uint4 a4 = *(const uint4*)(ebase + ((size_t)(base + col) << 5) +
                                   ((grp & 1) << 4));
        bf16x8v afrag = __builtin_bit_cast(bf16x8v, a4);
#pragma unroll
        for (int cb = 0; cb < 8; ++cb) {
            f32x4v c = {bias[cb], bias[cb], bias[cb], bias[cb]};
            f32x4v ev = __builtin_amdgcn_mfma_f32_16x16x32_bf16(afrag, bfrag[cb],
                                                                c, 0, 0, 0);
#pragma unroll
            for (int r = 0; r < 4; ++r) {
                const int slot = grp * 4 + r;
                esm[slot][cb * 16 + col] = (slot < rem) ? ev[r] : -1e30f;
            }
        }
        // ---- Phase B: vectorized H gather + accumulate ----
#pragma unroll
        for (int i = 0; i < 8; ++i) {
            const int er = 2 * i + ep;
            const int eidx = base + er;
            const int src = CSRS[eidx < j1 ? eidx : (j1 - 1)];
            uint4 hv = *(const uint4*)(HB + (((size_t)(2 * src + s)) << 7) + co);
            const float4* ep4 = (const float4*)&esm[er][co];
            float4 e0 = ep4[0], e1 = ep4[1];
            acc[0] += fmaxf(b2f(hv.x & 0xffff) + e0.x, 0.f);
            acc[1] += fmaxf(b2f(hv.x >> 16)    + e0.y, 0.f);
            acc[2] += fmaxf(b2f(hv.y & 0xffff) + e0.z, 0.f);
            acc[3] += fmaxf(b2f(hv.y >> 16)    + e0.w, 0.f);
            acc[4] += fmaxf(b2f(hv.z & 0xffff) + e1.x, 0.f);
            acc[5] += fmaxf(b2f(hv.z >> 16)    + e1.y, 0.f);
            acc[6] += fmaxf(b2f(hv.w & 0xffff) + e1.z, 0.f);
            acc[7] += fmaxf(b2f(hv.w >> 16)    + e1.w, 0.f);
        }
    }
    // reduce across edge-parity halves, then write
#pragma unroll
    for (int i = 0; i < 8; ++i) acc[i] += __shfl_xor(acc[i], 32);
    if (lane < 32) {
        float* arow = AGG + (size_t)(2 * node + s) * 128 + co;
        float4 v0 = make_float4(acc[0], acc[1], acc[2], acc[3]);
        float4 v1 = make_float4(acc[4], acc[5], acc[6], acc[7]);
        ((float4*)arow)[0] = v0;
        ((float4*)arow)[1] = v1;
    }
}

// din=16: half-wave (32 lanes) per node.
__global__ __launch_bounds__(256)
void agg_gather16(const int* __restrict__ CSRS, const int* __restrict__ OFF,
                  const uint4* __restrict__ EABS, const float* __restrict__ WE,
                  const float* __restrict__ BE,
                  const unsigned short* __restrict__ HB,
                  float* __restrict__ AGG, int n) {
    const int l = threadIdx.x & 31;
    const int node = blockIdx.x * 8 + (threadIdx.x >> 5);
    if (node >= n) return;
    const int s = l >> 4;
    const int c = l & 15;
    unsigned int wh[8], wl[8];
#pragma unroll
    for (int t = 0; t < 8; ++t) {
        float a0 = WE[(2 * t) * 16 + c], a1 = WE[(2 * t + 1) * 16 + c];
        wh[t] = pack2(a0, a1);
        wl[t] = pack2(bres(a0), bres(a1));
    }
    const float bev = BE[c];
    float acc = 0.f;
    const int j0 = OFF[node], j1 = OFF[node + 1];
#pragma unroll 4
    for (int j = j0; j < j1; ++j) {
        int src = CSRS[j];
        uint4 p = EABS[(size_t)2 * j], q = EABS[(size_t)2 * j + 1];
        float ec = bev;
        dot2b(ec, p.x, wh[0]); dot2b(ec, p.y, wh[1]);
        dot2b(ec, p.z, wh[2]); dot2b(ec, p.w, wh[3]);
        dot2b(ec, q.x, wh[4]); dot2b(ec, q.y, wh[5]);
        dot2b(ec, q.z, wh[6]); dot2b(ec, q.w, wh[7]);
        dot2b(ec, p.x, wl[0]); dot2b(ec, p.y, wl[1]);
        dot2b(ec, p.z, wl[2]); dot2b(ec, p.w, wl[3]);
        dot2b(ec, q.x, wl[4]); dot2b(ec, q.y, wl[5]);
        dot2b(ec, q.z, wl[6]); dot2b(ec, q.w, wl[7]);
        float hv = b2f(HB[(size_t)(2 * src + s) * 16 + c]);
        acc += fmaxf(hv + ec, 0.f);
    }
    AGG[(size_t)(2 * node + s) * 16 + c] = acc;
}

// Fused node MLP (VALU, proven r5): OUT = maybe_relu(relu((X[+AGG])@W1+b1)@W2+b2)
template <int DIN, int DOUT, bool RELU_OUT, bool HAS_AGG, bool WRITE_B>
__global__ __launch_bounds__(256)
void node_mlp(const float* __restrict__ X, const float* __restrict__ AGG,
              const float* __restrict__ W1, const float* __restrict__ B1,
              const float* __restrict__ W2, const float* __restrict__ B2,
              float* __restrict__ OUT, unsigned short* __restrict__ OUTB,
              int rows) {
    __shared__ float sX[32 * DIN];
    __shared__ float sH[32 * DHID];
    const int tid = threadIdx.x;

    for (int row0 = blockIdx.x * 32; row0 < rows; row0 += gridDim.x * 32) {
        __syncthreads();
        constexpr int DIN4 = DIN / 4;
        for (int i = tid; i < 32 * DIN4; i += 256) {
            int r = i / DIN4, k4 = i % DIN4;
            int gr = row0 + r;
            float4 v = make_float4(0.f, 0.f, 0.f, 0.f);
            if (gr < rows) {
                v = ((const float4*)X)[(size_t)gr * DIN4 + k4];
                if (HAS_AGG) {
                    float4 a = ((const float4*)AGG)[(size_t)gr * DIN4 + k4];
                    v.x += a.x; v.y += a.y; v.z += a.z; v.w += a.w;
                }
            }
            ((float4*)sX)[i] = v;
        }
        __syncthreads();
        {
            const int c = tid & 63;
            const int r0 = tid >> 6;
            float acc[8][2];
            const float b1a = B1[c], b1b = B1[c + 64];
#pragma unroll
            for (int j = 0; j < 8; ++j) {
                acc[j][0] = b1a;
                acc[j][1] = b1b;
            }
#pragma unroll 2
            for (int k4 = 0; k4 < DIN / 4; ++k4) {
                const int k = 4 * k4;
                float wa[4], wb[4];
#pragma unroll
                for (int kk = 0; kk < 4; ++kk) {
                    wa[kk] = W1[(k + kk) * DHID + c];
                    wb[kk] = W1[(k + kk) * DHID + c + 64];
                }
#pragma unroll
                for (int j = 0; j < 8; ++j) {
                    float4 xv = ((const float4*)sX)[((r0 + 4 * j) * DIN + k) >> 2];
                    acc[j][0] += xv.x * wa[0]; acc[j][1] += xv.x * wb[0];
                    acc[j][0] += xv.y * wa[1]; acc[j][1] += xv.y * wb[1];
                    acc[j][0] += xv.z * wa[2]; acc[j][1] += xv.z * wb[2];
                    acc[j][0] += xv.w * wa[3]; acc[j][1] += xv.w * wb[3];
                }
            }
#pragma unroll
            for (int j = 0; j < 8; ++j) {
                int r = r0 + 4 * j;
                sH[r * DHID + c] = fmaxf(acc[j][0], 0.f);
                sH[r * DHID + c + 64] = fmaxf(acc[j][1], 0.f);
            }
        }
        __syncthreads();
        {
            constexpr int HALF = DOUT / 2;
            constexpr int RP = 256 / HALF;
            constexpr int ITER = 32 / RP;
            const int c = tid % HALF;
            const int r0 = tid / HALF;
            float acc[ITER][2];
            const float bz0 = B2[c], bz1 = B2[c + HALF];
#pragma unroll
            for (int j = 0; j < ITER; ++j) {
                acc[j][0] = bz0;
                acc[j][1] = bz1;
            }
#pragma unroll 2
            for (int k4 = 0; k4 < DHID / 4; ++k4) {
                const int k = 4 * k4;
                float wa[4], wb[4];
#pragma unroll
                for (int kk = 0; kk < 4; ++kk) {
                    wa[kk] = W2[(k + kk) * DOUT + c];
                    wb[kk] = W2[(k + kk) * DOUT + c + HALF];
                }
#pragma unroll
                for (int j = 0; j < ITER; ++j) {
                    float4 hv = ((const float4*)sH)[((r0 + RP * j) * DHID + k) >> 2];
                    acc[j][0] += hv.x * wa[0]; acc[j][1] += hv.x * wb[0];
                    acc[j][0] += hv.y * wa[1]; acc[j][1] += hv.y * wb[1];
                    acc[j][0] += hv.z * wa[2]; acc[j][1] += hv.z * wb[2];
                    acc[j][0] += hv.w * wa[3]; acc[j][1] += hv.w * wb[3];
                }
            }
#pragma unroll
            for (int j = 0; j < ITER; ++j) {
                int gr = row0 + r0 + RP * j;
                if (gr < rows) {
                    float o0 = acc[j][0], o1 = acc[j][1];
                    if (RELU_OUT) {
                        o0 = fmaxf(o0, 0.f);
                        o1 = fmaxf(o1, 0.f);
                    }
                    OUT[(size_t)gr * DOUT + c] = o0;
                    OUT[(size_t)gr * DOUT + c + HALF] = o1;
                    if (WRITE_B) {
                        OUTB[(size_t)gr * DOUT + c] = f2b(o0);
                        OUTB[(size_t)gr * DOUT + c + HALF] = f2b(o1);
                    }
                }
            }
        }
    }
}

extern "C" void kernel_launch(void* const* d_in, const int* in_sizes, int n_in,
                              void* d_out, int out_size, void* d_ws, size_t ws_size,
                              hipStream_t stream) {
    const float* x = (const float*)d_in[0];
    const float* ea = (const float*)d_in[1];
    const int* esrc = (const int*)d_in[2];
    const int* edst = (const int*)d_in[3];
    const float* we0 = (const float*)d_in[4];
    const float* be0 = (const float*)d_in[5];
    const float* w10 = (const float*)d_in[6];
    const float* b10 = (const float*)d_in[7];
    const float* w20 = (const float*)d_in[8];
    const float* b20 = (const float*)d_in[9];
    const float* we1 = (const float*)d_in[10];
    const float* be1 = (const float*)d_in[11];
    const float* w11 = (const float*)d_in[12];
    const float* b11 = (const float*)d_in[13];
    const float* w21 = (const float*)d_in[14];
    const float* b21 = (const float*)d_in[15];
    const float* we2 = (const float*)d_in[16];
    const float* be2 = (const float*)d_in[17];
    const float* w12 = (const float*)d_in[18];
    const float* b12 = (const float*)d_in[19];
    const float* w22 = (const float*)d_in[20];
    const float* b22 = (const float*)d_in[21];
    const float* rw1 = (const float*)d_in[22];
    const float* rb1 = (const float*)d_in[23];
    const float* rw2 = (const float*)d_in[24];
    const float* rb2 = (const float*)d_in[25];

    const int N = in_sizes[0] / 16;
    const int E = in_sizes[2];
    const int M = 2 * N;

    float* HA = (float*)d_ws;                        // M*128 f32
    float* HB = HA + (size_t)M * 128;                // M*128 f32
    float* AG = HB + (size_t)M * 128;                // M*128 f32
    unsigned short* Hb = (unsigned short*)(AG + (size_t)M * 128);  // M*128 bf16
    unsigned short* EABS = Hb + (size_t)M * 128;     // E*16 bf16, CSR order
    int* deg = (int*)(EABS + (size_t)E * 16);        // N
    int* off = deg + N;                              // N+1
    int* pos = off + N + 1;                          // N
    int* bsum = pos + N;                             // 256
    int* csrsrc = bsum + 256;                        // E

    const int ntiles = (M + 31) / 32;
    const int eblocks = (E + 255) / 256;
    const int nblocks = (N + 255) / 256;

    // ---- CSR build (once; shared by all 3 layers) ----
    hipMemsetAsync(deg, 0, (size_t)N * sizeof(int), stream);
    csr_count<<<eblocks, 256, 0, stream>>>(edst, deg, E);
    scan1<<<nblocks, 256, 0, stream>>>(deg, off, bsum, N);
    scan2<<<1, 256, 0, stream>>>(bsum, nblocks);
    scan3<<<nblocks, 256, 0, stream>>>(off, pos, bsum, deg, N);
    csr_fill<<<eblocks, 256, 0, stream>>>(esrc, edst, ea, pos, csrsrc,
                                          (uint4*)EABS, E);

    // H0 (M x 16), f32 + bf16
    init_h0<<<(N * 16 + 255) / 256, 256, 0, stream>>>(x, HA, Hb, N);

    // ---- layer 0 (din=16 -> 128) ----
    agg_gather16<<<(N + 7) / 8, 256, 0, stream>>>(csrsrc, off, (const uint4*)EABS,
                                                  we0, be0, Hb, AG, N);
    node_mlp<16, 128, true, true, true><<<ntiles, 256, 0, stream>>>(
        HA, AG, w10, b10, w20, b20, HB, Hb, M);

    // ---- layer 1 (128 -> 128) ----
    agg_gather128<<<(N + 3) / 4, 256, 0, stream>>>(csrsrc, off, EABS,
                                                   we1, be1, Hb, AG, N);
    node_mlp<128, 128, true, true, true><<<ntiles, 256, 0, stream>>>(
        HB, AG, w11, b11, w21, b21, HA, Hb, M);

    // ---- layer 2 (128 -> 64) ----
    agg_gather128<<<(N + 3) / 4, 256, 0, stream>>>(csrsrc, off, EABS,
                                                   we2, be2, Hb, AG, N);
    node_mlp<128, 64, false, true, false><<<ntiles, 256, 0, stream>>>(
        HA, AG, w12, b12, w22, b22, HB, nullptr, M);

    // ---- sign sum + readout (64 -> 128 -> 16) ----
    sum_signs<<<(N * 64 + 255) / 256, 256, 0, stream>>>(HB, AG, N);
    node_mlp<64, 16, false, false, false><<<(N + 31) / 32, 256, 0, stream>>>(
        AG, nullptr, rw1, rb1, rw2, rb2, (float*)d_out, nullptr, N);
}